// Round 3
// baseline (601.136 us; speedup 1.0000x reference)
//
#include <hip/hip_runtime.h>
#include <hip/hip_fp16.h>
#include <hip/hip_cooperative_groups.h>
#include <math.h>

namespace cg = cooperative_groups;

#define BLOCK 256
#define OPT 4                      // observations per thread per chunk
#define CHUNK (BLOCK * OPT)        // 1024 observations per chunk
#define CPB 4                      // chunks per block -> 4096 obs/block, 8 KB LDS

__device__ __forceinline__ float fast_rcp(float x) {
    return __builtin_amdgcn_rcpf(x);
}

// ---------------------------------------------------------------------------
// block-wide sum of two floats; result valid in thread 0
// ---------------------------------------------------------------------------
__device__ __forceinline__ void block_reduce2(float& a, float& b) {
    #pragma unroll
    for (int off = 32; off > 0; off >>= 1) {
        a += __shfl_down(a, off, 64);
        b += __shfl_down(b, off, 64);
    }
    __shared__ float sa[BLOCK / 64], sb[BLOCK / 64];
    const int wid  = threadIdx.x >> 6;
    const int lane = threadIdx.x & 63;
    if (lane == 0) { sa[wid] = a; sb[wid] = b; }
    __syncthreads();
    if (threadIdx.x == 0) {
        a = sa[0]; b = sb[0];
        #pragma unroll
        for (int w = 1; w < BLOCK / 64; ++w) { a += sa[w]; b += sb[w]; }
    }
    __syncthreads();   // safe reuse of sa/sb on a second call
}

// One chunk's per-thread input registers: 144 B
struct ChunkRegs {
    float4 p0, p1, p2;   // u_pred: 4 obs x 3 comps
    float4 o0, o1, o2;   // u_obs
    float4 mp, mo, sg;   // mag_pred, mag_obs, sigma_mag
};

__device__ __forceinline__ ChunkRegs load_chunk(
    const float* __restrict__ u_pred, const float* __restrict__ u_obs,
    const float* __restrict__ mag_pred, const float* __restrict__ mag_obs,
    const float* __restrict__ sigma_mag, size_t base, int t)
{
    ChunkRegs r;
    const float4* up4 = (const float4*)(u_pred + 3 * base);
    const float4* uo4 = (const float4*)(u_obs  + 3 * base);
    r.p0 = up4[3 * t + 0]; r.p1 = up4[3 * t + 1]; r.p2 = up4[3 * t + 2];
    r.o0 = uo4[3 * t + 0]; r.o1 = uo4[3 * t + 1]; r.o2 = uo4[3 * t + 2];
    r.mp = ((const float4*)(mag_pred  + base))[t];
    r.mo = ((const float4*)(mag_obs   + base))[t];
    r.sg = ((const float4*)(sigma_mag + base))[t];
    return r;
}

// ---------------------------------------------------------------------------
// Fused cooperative kernel, 2048 blocks (8/CU co-resident, 32 waves/CU):
//   phase A: stream inputs (pipelined chunk loads), cache ep as fp16 in LDS
//   grid.sync()
//   phase B: per-segment constants from acc, log_like & hits from LDS
// ---------------------------------------------------------------------------
__global__ __launch_bounds__(BLOCK, 8)
void fused_kernel(const float* __restrict__ u_pred,
                  const float* __restrict__ u_obs,
                  const float* __restrict__ mag_pred,
                  const float* __restrict__ mag_obs,
                  const float* __restrict__ sigma_mag,
                  const float* __restrict__ Rparam,
                  const float* __restrict__ thresh_raw,
                  const float* __restrict__ log_range,
                  const float* __restrict__ num_hits,
                  float*       __restrict__ acc,      // [2*B]
                  float*       __restrict__ out,      // [2*B]
                  int B, int rowLen, int blocksPerSeg, float ts2min)
{
    __shared__ __half eps[CPB * CHUNK];   // 8 KB: this block's ep cache

    const int seg = blockIdx.x / blocksPerSeg;
    const int blk = blockIdx.x - seg * blocksPerSeg;
    const long long segBase = (long long)seg * rowLen;

    const float thresh  = ts2min * __expf(thresh_raw[seg] * log_range[seg]);
    const float Rv      = Rparam[seg];
    const float lam     = 0.5f * thresh / (Rv * Rv);
    const float nlam_it = -lam * fast_rcp(thresh);   // e = exp(nlam_it * s2)

    float cnt = 0.f, pmsum = 0.f;
    const int t = threadIdx.x;
    const int off0 = blk * CPB * CHUNK;

    if (off0 + CPB * CHUNK <= rowLen) {
        // fast path: fully in-range; pipelined chunk loop (prefetch next)
        const size_t base0 = (size_t)(segBase + off0);
        ChunkRegs cur = load_chunk(u_pred, u_obs, mag_pred, mag_obs,
                                   sigma_mag, base0, t);
        #pragma unroll
        for (int c = 0; c < CPB; ++c) {
            ChunkRegs nxt;
            if (c + 1 < CPB)
                nxt = load_chunk(u_pred, u_obs, mag_pred, mag_obs, sigma_mag,
                                 base0 + (size_t)(c + 1) * CHUNK, t);
            const float* pp = (const float*)&cur.p0;   // 12 floats
            const float* oo = (const float*)&cur.o0;
            const float* mp = (const float*)&cur.mp;
            const float* mo = (const float*)&cur.mo;
            const float* sg = (const float*)&cur.sg;
            ushort4 hv;
            unsigned short* hp = (unsigned short*)&hv;
            #pragma unroll
            for (int j = 0; j < OPT; ++j) {
                const float dx = pp[3 * j]     - oo[3 * j];
                const float dy = pp[3 * j + 1] - oo[3 * j + 1];
                const float dz = pp[3 * j + 2] - oo[3 * j + 2];
                const float s2 = dx * dx + dy * dy + dz * dz;
                const float z  = (mp[j] - mo[j]) * fast_rcp(sg[j]);
                const float pm = __expf(-0.5f * z * z);
                const bool close = s2 < thresh;
                const float e  = close ? __expf(nlam_it * s2) : 0.f;
                hp[j] = __half_as_ushort(__float2half(e * pm));
                cnt   += close ? 1.f : 0.f;
                pmsum += close ? pm  : 0.f;
            }
            ((ushort4*)(eps + (size_t)c * CHUNK))[t] = hv;   // LDS, conflict-free
            cur = nxt;
        }
    } else {
        // tail path: predicated scalar loads
        for (int c = 0; c < CPB; ++c) {
            for (int j = 0; j < OPT; ++j) {
                const int o = off0 + c * CHUNK + t * OPT + j;
                float val = 0.f;
                if (o < rowLen) {
                    const size_t i = (size_t)(segBase + o);
                    const float dx = u_pred[3 * i]     - u_obs[3 * i];
                    const float dy = u_pred[3 * i + 1] - u_obs[3 * i + 1];
                    const float dz = u_pred[3 * i + 2] - u_obs[3 * i + 2];
                    const float s2 = dx * dx + dy * dy + dz * dz;
                    const float z  = (mag_pred[i] - mag_obs[i]) * fast_rcp(sigma_mag[i]);
                    const float pm = __expf(-0.5f * z * z);
                    if (s2 < thresh) {
                        val = __expf(nlam_it * s2) * pm;
                        cnt   += 1.f;
                        pmsum += pm;
                    }
                }
                eps[c * CHUNK + t * OPT + j] = __float2half(val);
            }
        }
    }

    block_reduce2(cnt, pmsum);
    if (t == 0) {
        atomicAdd(&acc[2 * seg],     cnt);
        atomicAdd(&acc[2 * seg + 1], pmsum);
    }

    cg::this_grid().sync();

    // ---- phase B: per-segment constants now final ----
    const float rlc        = acc[2 * seg];
    const float h          = num_hits[seg] * fast_rcp(rlc);
    const float inv_pm_den = rlc * fast_rcp(acc[2 * seg + 1]);
    const float coef       = lam * fast_rcp(1.f - __expf(-lam));
    const float one_m_h    = 1.f - h;
    const float K1         = h * coef * inv_pm_den;   // phit = K1 * ep

    float ll = 0.f, ht = 0.f;
    #pragma unroll
    for (int c = 0; c < CPB; ++c) {
        const ushort4 hv = ((const ushort4*)(eps + (size_t)c * CHUNK))[t];
        const unsigned short* hp = (const unsigned short*)&hv;
        #pragma unroll
        for (int j = 0; j < OPT; ++j) {
            const float e = __half2float(__ushort_as_half(hp[j]));
            if (e > 0.f) {
                const float phit = K1 * e;
                const float p    = phit + one_m_h;
                ll += __logf(p);
                ht += phit * fast_rcp(p);
            }
        }
    }

    block_reduce2(ll, ht);
    if (t == 0) {
        atomicAdd(&out[seg],     ll);
        atomicAdd(&out[B + seg], ht);
    }
}

// ---------------------------------------------------------------------------
// Fallback two-pass path (used only if cooperative launch is refused)
// ---------------------------------------------------------------------------
__global__ __launch_bounds__(BLOCK)
void pass1_kernel(const float* __restrict__ u_pred,
                  const float* __restrict__ u_obs,
                  const float* __restrict__ mag_pred,
                  const float* __restrict__ mag_obs,
                  const float* __restrict__ sigma_mag,
                  const float* __restrict__ Rparam,
                  const float* __restrict__ thresh_raw,
                  const float* __restrict__ log_range,
                  float*       __restrict__ acc,      // [2*B]
                  __half*      __restrict__ epc,      // [N] fp16 cache
                  int rowLen, int blocksPerSeg, float ts2min)
{
    const int seg = blockIdx.x / blocksPerSeg;
    const int blk = blockIdx.x - seg * blocksPerSeg;
    const long long segBase = (long long)seg * rowLen;

    const float thresh  = ts2min * __expf(thresh_raw[seg] * log_range[seg]);
    const float Rv      = Rparam[seg];
    const float lam     = 0.5f * thresh / (Rv * Rv);
    const float nlam_it = -lam * fast_rcp(thresh);

    float cnt = 0.f, pmsum = 0.f;
    const int t = threadIdx.x;
    const int off0 = blk * CPB * CHUNK;

    if (off0 + CPB * CHUNK <= rowLen) {
        const size_t base0 = (size_t)(segBase + off0);
        ChunkRegs cur = load_chunk(u_pred, u_obs, mag_pred, mag_obs,
                                   sigma_mag, base0, t);
        #pragma unroll
        for (int c = 0; c < CPB; ++c) {
            ChunkRegs nxt;
            if (c + 1 < CPB)
                nxt = load_chunk(u_pred, u_obs, mag_pred, mag_obs, sigma_mag,
                                 base0 + (size_t)(c + 1) * CHUNK, t);
            const float* pp = (const float*)&cur.p0;
            const float* oo = (const float*)&cur.o0;
            const float* mp = (const float*)&cur.mp;
            const float* mo = (const float*)&cur.mo;
            const float* sg = (const float*)&cur.sg;
            ushort4 hv;
            unsigned short* hp = (unsigned short*)&hv;
            #pragma unroll
            for (int j = 0; j < OPT; ++j) {
                const float dx = pp[3 * j]     - oo[3 * j];
                const float dy = pp[3 * j + 1] - oo[3 * j + 1];
                const float dz = pp[3 * j + 2] - oo[3 * j + 2];
                const float s2 = dx * dx + dy * dy + dz * dz;
                const float z  = (mp[j] - mo[j]) * fast_rcp(sg[j]);
                const float pm = __expf(-0.5f * z * z);
                const bool close = s2 < thresh;
                const float e  = close ? __expf(nlam_it * s2) : 0.f;
                hp[j] = __half_as_ushort(__float2half(e * pm));
                cnt   += close ? 1.f : 0.f;
                pmsum += close ? pm  : 0.f;
            }
            ((ushort4*)(epc + base0 + (size_t)c * CHUNK))[t] = hv;
            cur = nxt;
        }
    } else {
        for (int c = 0; c < CPB; ++c) {
            const int off = off0 + c * CHUNK;
            if (off >= rowLen) break;
            for (int j = 0; j < OPT; ++j) {
                const int o = off + t * OPT + j;
                if (o >= rowLen) break;
                const size_t i = (size_t)(segBase + o);
                const float dx = u_pred[3 * i]     - u_obs[3 * i];
                const float dy = u_pred[3 * i + 1] - u_obs[3 * i + 1];
                const float dz = u_pred[3 * i + 2] - u_obs[3 * i + 2];
                const float s2 = dx * dx + dy * dy + dz * dz;
                const float z  = (mag_pred[i] - mag_obs[i]) * fast_rcp(sigma_mag[i]);
                const float pm = __expf(-0.5f * z * z);
                const bool close = s2 < thresh;
                const float e  = close ? __expf(nlam_it * s2) : 0.f;
                epc[i] = __float2half(e * pm);
                cnt   += close ? 1.f : 0.f;
                pmsum += close ? pm  : 0.f;
            }
        }
    }

    block_reduce2(cnt, pmsum);
    if (threadIdx.x == 0) {
        atomicAdd(&acc[2 * seg],     cnt);
        atomicAdd(&acc[2 * seg + 1], pmsum);
    }
}

__global__ __launch_bounds__(BLOCK)
void pass2_kernel(const float* __restrict__ num_hits,
                  const float* __restrict__ Rparam,
                  const float* __restrict__ thresh_raw,
                  const float* __restrict__ log_range,
                  const float* __restrict__ acc,
                  const __half* __restrict__ epc,
                  float* __restrict__ out, int B,
                  int rowLen, int blocksPerSeg, float ts2min)
{
    const int seg = blockIdx.x / blocksPerSeg;
    const int blk = blockIdx.x - seg * blocksPerSeg;
    const long long segBase = (long long)seg * rowLen;

    const float thresh     = ts2min * __expf(thresh_raw[seg] * log_range[seg]);
    const float rlc        = acc[2 * seg];
    const float h          = num_hits[seg] * fast_rcp(rlc);
    const float inv_pm_den = rlc * fast_rcp(acc[2 * seg + 1]);
    const float Rv         = Rparam[seg];
    const float lam        = 0.5f * thresh / (Rv * Rv);
    const float coef       = lam * fast_rcp(1.f - __expf(-lam));
    const float one_m_h    = 1.f - h;
    const float K1         = h * coef * inv_pm_den;

    float ll = 0.f, ht = 0.f;
    const int t = threadIdx.x;

    #pragma unroll 1
    for (int c = 0; c < CPB; ++c) {
        const int off = (blk * CPB + c) * CHUNK;
        if (off >= rowLen) break;
        if (off + CHUNK <= rowLen) {
            const size_t base = (size_t)(segBase + off);
            const ushort4 hv = ((const ushort4*)(epc + base))[t];
            const unsigned short* hp = (const unsigned short*)&hv;
            #pragma unroll
            for (int j = 0; j < OPT; ++j) {
                const float e = __half2float(__ushort_as_half(hp[j]));
                if (e > 0.f) {
                    const float phit = K1 * e;
                    const float p    = phit + one_m_h;
                    ll += __logf(p);
                    ht += phit * fast_rcp(p);
                }
            }
        } else {
            for (int j = 0; j < OPT; ++j) {
                const int o = off + t * OPT + j;
                if (o >= rowLen) break;
                const float e = __half2float(epc[segBase + o]);
                if (e > 0.f) {
                    const float phit = K1 * e;
                    const float p    = phit + one_m_h;
                    ll += __logf(p);
                    ht += phit * fast_rcp(p);
                }
            }
        }
    }

    block_reduce2(ll, ht);
    if (threadIdx.x == 0) {
        atomicAdd(&out[seg],     ll);
        atomicAdd(&out[B + seg], ht);
    }
}

// ---------------------------------------------------------------------------
extern "C" void kernel_launch(void* const* d_in, const int* in_sizes, int n_in,
                              void* d_out, int out_size, void* d_ws, size_t ws_size,
                              hipStream_t stream) {
    const float* u_pred     = (const float*)d_in[0];   // [N,3]
    const float* num_hits   = (const float*)d_in[1];   // [B]
    const float* Rparam     = (const float*)d_in[2];   // [B]
    const float* mag_pred   = (const float*)d_in[3];   // [N]
    const float* sigma_mag  = (const float*)d_in[4];   // [N]
    const float* thresh_raw = (const float*)d_in[5];   // [B]
    const float* log_range  = (const float*)d_in[6];   // [B]
    const float* u_obs      = (const float*)d_in[7];   // [N,3]
    const float* mag_obs    = (const float*)d_in[8];   // [N]
    // d_in[9] segment_ids unused: segments are contiguous uniform rows

    const int B      = in_sizes[1];
    const int N      = in_sizes[3];
    const int rowLen = N / B;

    float* out = (float*)d_out;

    // ws layout: acc (2*B floats, padded to 1 KB) | fp16 ep cache [N] (fallback only)
    const size_t accBytes = 1024;
    float*  acc = (float*)d_ws;
    __half* epc = (__half*)((char*)d_ws + accBytes);

    const int obsPerBlock = CHUNK * CPB;
    const int blocksPerSeg = (rowLen + obsPerBlock - 1) / obsPerBlock;
    const int grid = B * blocksPerSeg;     // 2048 for N=8.4M: 8 blocks/CU

    const double ang = (10.0 / 3600.0) * (M_PI / 180.0);
    const double chord = 2.0 * sin(0.5 * ang);
    const float ts2min = (float)(chord * chord);

    hipMemsetAsync(d_out, 0, (size_t)out_size * sizeof(float), stream);
    hipMemsetAsync(d_ws, 0, accBytes, stream);

    // cooperative fused launch (2048 blocks -> 8/CU co-resident, 32 waves/CU)
    int Bv = B, rl = rowLen, bps = blocksPerSeg;
    float ts = ts2min;
    void* args[] = {(void*)&u_pred, (void*)&u_obs, (void*)&mag_pred,
                    (void*)&mag_obs, (void*)&sigma_mag, (void*)&Rparam,
                    (void*)&thresh_raw, (void*)&log_range, (void*)&num_hits,
                    (void*)&acc, (void*)&out, (void*)&Bv, (void*)&rl,
                    (void*)&bps, (void*)&ts};
    hipError_t err = hipLaunchCooperativeKernel((void*)fused_kernel,
                                                dim3(grid), dim3(BLOCK),
                                                args, 0, stream);
    if (err != hipSuccess) {
        // fallback: original two-pass structure
        pass1_kernel<<<grid, BLOCK, 0, stream>>>(
            u_pred, u_obs, mag_pred, mag_obs, sigma_mag,
            Rparam, thresh_raw, log_range, acc, epc, rowLen, blocksPerSeg, ts2min);
        pass2_kernel<<<grid, BLOCK, 0, stream>>>(
            num_hits, Rparam, thresh_raw, log_range, acc, epc,
            out, B, rowLen, blocksPerSeg, ts2min);
    }
}

// Round 5
// 330.704 us; speedup vs baseline: 1.8177x; 1.8177x over previous
//
#include <hip/hip_runtime.h>
#include <hip/hip_fp16.h>
#include <math.h>

#define BLOCK 256
#define OPT 4                      // observations per thread per tile/chunk
#define CHUNK (BLOCK * OPT)        // 1024 observations per block-chunk (pass2)
#define CPB 4                      // chunks per block -> 4096 obs/block
#define TILE 256                   // observations per wave-tile (pass1 staging)
#define TILE_BYTES 9216            // u_pred 3K + u_obs 3K + mp/mo/sg 1K each

__device__ __forceinline__ float fast_rcp(float x) {
    return __builtin_amdgcn_rcpf(x);
}

typedef const __attribute__((address_space(1))) unsigned int* gas_ptr;
typedef __attribute__((address_space(3))) unsigned int* las_ptr;

// async global->LDS, 16 B per lane. LDS dest is wave-uniform base (+lane*16 by HW),
// global source is per-lane.
__device__ __forceinline__ void glds16(const void* g, void* l) {
    __builtin_amdgcn_global_load_lds((gas_ptr)g, (las_ptr)l, 16, 0, 0);
}

// ---------------------------------------------------------------------------
// block-wide sum of two floats; result valid in thread 0
// ---------------------------------------------------------------------------
__device__ __forceinline__ void block_reduce2(float& a, float& b) {
    #pragma unroll
    for (int off = 32; off > 0; off >>= 1) {
        a += __shfl_down(a, off, 64);
        b += __shfl_down(b, off, 64);
    }
    __shared__ float sa[BLOCK / 64], sb[BLOCK / 64];
    const int wid  = threadIdx.x >> 6;
    const int lane = threadIdx.x & 63;
    if (lane == 0) { sa[wid] = a; sb[wid] = b; }
    __syncthreads();
    if (threadIdx.x == 0) {
        a = sa[0]; b = sb[0];
        #pragma unroll
        for (int w = 1; w < BLOCK / 64; ++w) { a += sa[w]; b += sb[w]; }
    }
}

// ---------------------------------------------------------------------------
// Pass 1: wave-private double-buffered global_load_lds staging.
// Each wave owns 1024 contiguous obs = 4 tiles of 256. Per tile: 9 glds16
// (1 KB each, fully coalesced). Counted vmcnt(9) keeps next tile's 9 loads
// in flight while consuming the current tile. No barriers (wave-private bufs).
// ---------------------------------------------------------------------------
__global__ __launch_bounds__(BLOCK)
void pass1_kernel(const float* __restrict__ u_pred,
                  const float* __restrict__ u_obs,
                  const float* __restrict__ mag_pred,
                  const float* __restrict__ mag_obs,
                  const float* __restrict__ sigma_mag,
                  const float* __restrict__ Rparam,
                  const float* __restrict__ thresh_raw,
                  const float* __restrict__ log_range,
                  float*       __restrict__ acc,      // [2*B]
                  __half*      __restrict__ epc,      // [N] fp16 cache
                  int rowLen, int blocksPerSeg, float ts2min)
{
    // 4 waves x 2 buffers x 9216 B = 72 KB (float4-aligned)
    __shared__ float4 stage[4][2][TILE_BYTES / 16];

    const int seg = blockIdx.x / blocksPerSeg;
    const int blk = blockIdx.x - seg * blocksPerSeg;
    const long long segBase = (long long)seg * rowLen;

    const float thresh  = ts2min * __expf(thresh_raw[seg] * log_range[seg]);
    const float Rv      = Rparam[seg];
    const float lam     = 0.5f * thresh / (Rv * Rv);
    const float nlam_it = -lam * fast_rcp(thresh);   // e = exp(nlam_it * s2)

    float cnt = 0.f, pmsum = 0.f;
    const int t    = threadIdx.x;
    const int w    = t >> 6;          // wave id 0..3
    const int l    = t & 63;          // lane id
    const int off0 = blk * CPB * CHUNK;   // 4096 obs per block

    if (off0 + CPB * CHUNK <= rowLen) {
        // ---- fast path ----
        const long long wbase = segBase + off0 + w * (4 * TILE); // wave's 1024 obs

        // stage tile tau into buffer p (wave-private)
        #define STAGE(tau, p) do {                                               \
            const long long tb = wbase + (tau) * TILE;                           \
            char* lb = (char*)&stage[w][(p)][0];                                 \
            const char* upg = (const char*)u_pred + tb * 12;                     \
            const char* uog = (const char*)u_obs  + tb * 12;                     \
            glds16(upg +    0 + l * 16, lb +    0);                              \
            glds16(upg + 1024 + l * 16, lb + 1024);                              \
            glds16(upg + 2048 + l * 16, lb + 2048);                              \
            glds16(uog +    0 + l * 16, lb + 3072);                              \
            glds16(uog + 1024 + l * 16, lb + 4096);                              \
            glds16(uog + 2048 + l * 16, lb + 5120);                              \
            glds16((const char*)mag_pred  + tb * 4 + l * 16, lb + 6144);         \
            glds16((const char*)mag_obs   + tb * 4 + l * 16, lb + 7168);         \
            glds16((const char*)sigma_mag + tb * 4 + l * 16, lb + 8192);         \
        } while (0)

        // consume tile tau from buffer p.
        // NOTE: read straight from LDS via per-lane pointers (ds_read), never
        // through &local_float4 pointer-arithmetic (UB — caused round-4 NaN).
        #define CONSUME(tau, p) do {                                             \
            const char* lb = (const char*)&stage[w][(p)][0];                     \
            const float* up = (const float*)(lb + 48 * l);                       \
            const float* oo = (const float*)(lb + 3072 + 48 * l);                \
            const float* mp = (const float*)(lb + 6144 + 16 * l);                \
            const float* mo = (const float*)(lb + 7168 + 16 * l);                \
            const float* sg = (const float*)(lb + 8192 + 16 * l);                \
            ushort4 hv;                                                          \
            unsigned short* hp = (unsigned short*)&hv;                           \
            _Pragma("unroll")                                                    \
            for (int j = 0; j < OPT; ++j) {                                      \
                const float dx = up[3 * j]     - oo[3 * j];                      \
                const float dy = up[3 * j + 1] - oo[3 * j + 1];                  \
                const float dz = up[3 * j + 2] - oo[3 * j + 2];                  \
                const float s2 = dx * dx + dy * dy + dz * dz;                    \
                const float z  = (mp[j] - mo[j]) * fast_rcp(sg[j]);              \
                const float pm = __expf(-0.5f * z * z);                          \
                const bool close = s2 < thresh;                                  \
                const float e  = close ? __expf(nlam_it * s2) : 0.f;             \
                hp[j] = __half_as_ushort(__float2half(e * pm));                  \
                cnt   += close ? 1.f : 0.f;                                      \
                pmsum += close ? pm  : 0.f;                                      \
            }                                                                    \
            ((ushort4*)(epc + wbase + (tau) * TILE))[l] = hv;                    \
        } while (0)

        STAGE(0, 0);

        STAGE(1, 1);
        asm volatile("s_waitcnt vmcnt(9)" ::: "memory");
        CONSUME(0, 0);

        STAGE(2, 0);
        asm volatile("s_waitcnt vmcnt(9)" ::: "memory");
        CONSUME(1, 1);

        STAGE(3, 1);
        asm volatile("s_waitcnt vmcnt(9)" ::: "memory");
        CONSUME(2, 0);

        asm volatile("s_waitcnt vmcnt(0)" ::: "memory");
        CONSUME(3, 1);

        #undef STAGE
        #undef CONSUME
    } else {
        // tail path: scalar with bounds checks (unused for rowLen % 4096 == 0)
        for (int c = 0; c < CPB; ++c) {
            const int off = off0 + c * CHUNK;
            if (off >= rowLen) break;
            for (int j = 0; j < OPT; ++j) {
                const int o = off + t * OPT + j;
                if (o >= rowLen) break;
                const size_t i = (size_t)(segBase + o);
                const float dx = u_pred[3 * i]     - u_obs[3 * i];
                const float dy = u_pred[3 * i + 1] - u_obs[3 * i + 1];
                const float dz = u_pred[3 * i + 2] - u_obs[3 * i + 2];
                const float s2 = dx * dx + dy * dy + dz * dz;
                const float z  = (mag_pred[i] - mag_obs[i]) * fast_rcp(sigma_mag[i]);
                const float pm = __expf(-0.5f * z * z);
                const bool close = s2 < thresh;
                const float e  = close ? __expf(nlam_it * s2) : 0.f;
                epc[i] = __float2half(e * pm);
                cnt   += close ? 1.f : 0.f;
                pmsum += close ? pm  : 0.f;
            }
        }
    }

    block_reduce2(cnt, pmsum);
    if (threadIdx.x == 0) {
        atomicAdd(&acc[2 * seg],     cnt);
        atomicAdd(&acc[2 * seg + 1], pmsum);
    }
}

// ---------------------------------------------------------------------------
// Pass 2: stream the 2 B/obs cache (L2/L3-resident); log_like and hits.
// ---------------------------------------------------------------------------
__global__ __launch_bounds__(BLOCK)
void pass2_kernel(const float* __restrict__ num_hits,
                  const float* __restrict__ Rparam,
                  const float* __restrict__ thresh_raw,
                  const float* __restrict__ log_range,
                  const float* __restrict__ acc,
                  const __half* __restrict__ epc,
                  float* __restrict__ out, int B,
                  int rowLen, int blocksPerSeg, float ts2min)
{
    const int seg = blockIdx.x / blocksPerSeg;
    const int blk = blockIdx.x - seg * blocksPerSeg;
    const long long segBase = (long long)seg * rowLen;

    const float thresh     = ts2min * __expf(thresh_raw[seg] * log_range[seg]);
    const float rlc        = acc[2 * seg];
    const float h          = num_hits[seg] * fast_rcp(rlc);
    const float inv_pm_den = rlc * fast_rcp(acc[2 * seg + 1]);
    const float Rv         = Rparam[seg];
    const float lam        = 0.5f * thresh / (Rv * Rv);
    const float coef       = lam * fast_rcp(1.f - __expf(-lam));
    const float one_m_h    = 1.f - h;
    const float K1         = h * coef * inv_pm_den;   // phit = K1 * ep

    float ll = 0.f, ht = 0.f;
    const int t = threadIdx.x;

    #pragma unroll 1
    for (int c = 0; c < CPB; ++c) {
        const int off = (blk * CPB + c) * CHUNK;
        if (off >= rowLen) break;
        if (off + CHUNK <= rowLen) {
            const size_t base = (size_t)(segBase + off);
            const ushort4 hv = ((const ushort4*)(epc + base))[t];
            const unsigned short* hp = (const unsigned short*)&hv;
            #pragma unroll
            for (int j = 0; j < OPT; ++j) {
                const float e = __half2float(__ushort_as_half(hp[j]));
                if (e > 0.f) {
                    const float phit = K1 * e;
                    const float p    = phit + one_m_h;
                    ll += __logf(p);
                    ht += phit * fast_rcp(p);
                }
            }
        } else {
            for (int j = 0; j < OPT; ++j) {
                const int o = off + t * OPT + j;
                if (o >= rowLen) break;
                const float e = __half2float(epc[segBase + o]);
                if (e > 0.f) {
                    const float phit = K1 * e;
                    const float p    = phit + one_m_h;
                    ll += __logf(p);
                    ht += phit * fast_rcp(p);
                }
            }
        }
    }

    block_reduce2(ll, ht);
    if (threadIdx.x == 0) {
        atomicAdd(&out[seg],     ll);
        atomicAdd(&out[B + seg], ht);
    }
}

// ---------------------------------------------------------------------------
extern "C" void kernel_launch(void* const* d_in, const int* in_sizes, int n_in,
                              void* d_out, int out_size, void* d_ws, size_t ws_size,
                              hipStream_t stream) {
    const float* u_pred     = (const float*)d_in[0];   // [N,3]
    const float* num_hits   = (const float*)d_in[1];   // [B]
    const float* Rparam     = (const float*)d_in[2];   // [B]
    const float* mag_pred   = (const float*)d_in[3];   // [N]
    const float* sigma_mag  = (const float*)d_in[4];   // [N]
    const float* thresh_raw = (const float*)d_in[5];   // [B]
    const float* log_range  = (const float*)d_in[6];   // [B]
    const float* u_obs      = (const float*)d_in[7];   // [N,3]
    const float* mag_obs    = (const float*)d_in[8];   // [N]
    // d_in[9] segment_ids unused: segments are contiguous uniform rows

    const int B      = in_sizes[1];
    const int N      = in_sizes[3];
    const int rowLen = N / B;

    float* out = (float*)d_out;

    // ws layout: acc (2*B floats, padded to 1 KB) | fp16 ep cache [N]
    const size_t accBytes = 1024;
    float*  acc = (float*)d_ws;
    __half* epc = (__half*)((char*)d_ws + accBytes);

    const int obsPerBlock = CHUNK * CPB;
    const int blocksPerSeg = (rowLen + obsPerBlock - 1) / obsPerBlock;
    const int grid = B * blocksPerSeg;     // 2048 for rowLen=131072

    const double ang = (10.0 / 3600.0) * (M_PI / 180.0);
    const double chord = 2.0 * sin(0.5 * ang);
    const float ts2min = (float)(chord * chord);

    hipMemsetAsync(d_out, 0, (size_t)out_size * sizeof(float), stream);
    hipMemsetAsync(d_ws, 0, accBytes, stream);

    pass1_kernel<<<grid, BLOCK, 0, stream>>>(
        u_pred, u_obs, mag_pred, mag_obs, sigma_mag,
        Rparam, thresh_raw, log_range, acc, epc, rowLen, blocksPerSeg, ts2min);
    pass2_kernel<<<grid, BLOCK, 0, stream>>>(
        num_hits, Rparam, thresh_raw, log_range, acc, epc,
        out, B, rowLen, blocksPerSeg, ts2min);
}

// Round 6
// 327.243 us; speedup vs baseline: 1.8370x; 1.0106x over previous
//
#include <hip/hip_runtime.h>
#include <hip/hip_fp16.h>
#include <math.h>

#define BLOCK 256
#define OPT 4                      // observations per thread per chunk
#define CHUNK (BLOCK * OPT)        // 1024 observations per block-chunk
#define CPB 4                      // chunks per block -> 4096 obs/block

__device__ __forceinline__ float fast_rcp(float x) {
    return __builtin_amdgcn_rcpf(x);
}

// ---------------------------------------------------------------------------
// block-wide sum of two floats; result valid in thread 0
// ---------------------------------------------------------------------------
__device__ __forceinline__ void block_reduce2(float& a, float& b) {
    #pragma unroll
    for (int off = 32; off > 0; off >>= 1) {
        a += __shfl_down(a, off, 64);
        b += __shfl_down(b, off, 64);
    }
    __shared__ float sa[BLOCK / 64], sb[BLOCK / 64];
    const int wid  = threadIdx.x >> 6;
    const int lane = threadIdx.x & 63;
    if (lane == 0) { sa[wid] = a; sb[wid] = b; }
    __syncthreads();
    if (threadIdx.x == 0) {
        a = sa[0]; b = sb[0];
        #pragma unroll
        for (int w = 1; w < BLOCK / 64; ++w) { a += sa[w]; b += sb[w]; }
    }
}

// ---------------------------------------------------------------------------
// Pass 1: pure-register double-buffered streaming.
// __launch_bounds__(256,4) allows 128 VGPRs so BOTH chunk buffers (2 x 9
// float4 = 72 regs) stay live -> 9 KB/wave in flight, 16 waves/CU resident
// => ~144 KB/CU in flight (2x the round-5 LDS scheme, which was capped by
// LDS residency). Compiler inserts precise counted vmcnt for reg loads.
// ---------------------------------------------------------------------------
__global__ __launch_bounds__(BLOCK, 4)
void pass1_kernel(const float* __restrict__ u_pred,
                  const float* __restrict__ u_obs,
                  const float* __restrict__ mag_pred,
                  const float* __restrict__ mag_obs,
                  const float* __restrict__ sigma_mag,
                  const float* __restrict__ Rparam,
                  const float* __restrict__ thresh_raw,
                  const float* __restrict__ log_range,
                  float*       __restrict__ acc,      // [2*B]
                  __half*      __restrict__ epc,      // [N] fp16 cache
                  int rowLen, int blocksPerSeg, float ts2min)
{
    const int seg = blockIdx.x / blocksPerSeg;
    const int blk = blockIdx.x - seg * blocksPerSeg;
    const long long segBase = (long long)seg * rowLen;

    const float thresh  = ts2min * __expf(thresh_raw[seg] * log_range[seg]);
    const float Rv      = Rparam[seg];
    const float lam     = 0.5f * thresh / (Rv * Rv);
    const float nlam_it = -lam * fast_rcp(thresh);   // e = exp(nlam_it * s2)

    float cnt = 0.f, pmsum = 0.f;
    const int t    = threadIdx.x;
    const int off0 = blk * CPB * CHUNK;   // 4096 obs per block

    if (off0 + CPB * CHUNK <= rowLen) {
        // ---- fast path ----
        const size_t base0 = (size_t)(segBase + off0);
        const float4* up4 = (const float4*)(u_pred + 3 * base0);
        const float4* uo4 = (const float4*)(u_obs  + 3 * base0);
        const float4* mp4 = (const float4*)(mag_pred  + base0);
        const float4* mo4 = (const float4*)(mag_obs   + base0);
        const float4* sg4 = (const float4*)(sigma_mag + base0);

        // chunk c: u floats occupy 768 float4 per chunk; mags 256 per chunk.
        #define LOADC(c, P0, P1, P2, O0, O1, O2, MP, MO, SG) do {               \
            P0 = up4[(c) * 768 + 3 * t + 0];                                    \
            P1 = up4[(c) * 768 + 3 * t + 1];                                    \
            P2 = up4[(c) * 768 + 3 * t + 2];                                    \
            O0 = uo4[(c) * 768 + 3 * t + 0];                                    \
            O1 = uo4[(c) * 768 + 3 * t + 1];                                    \
            O2 = uo4[(c) * 768 + 3 * t + 2];                                    \
            MP = mp4[(c) * 256 + t];                                            \
            MO = mo4[(c) * 256 + t];                                            \
            SG = sg4[(c) * 256 + t];                                            \
        } while (0)

        // consume one chunk held in registers; static component extraction
        // (no pointer arithmetic across distinct locals -- round-4 lesson).
        #define CONSUME(c, P0, P1, P2, O0, O1, O2, MP, MO, SG) do {             \
            const float up_[12] = {P0.x, P0.y, P0.z, P0.w,                      \
                                   P1.x, P1.y, P1.z, P1.w,                      \
                                   P2.x, P2.y, P2.z, P2.w};                     \
            const float uo_[12] = {O0.x, O0.y, O0.z, O0.w,                      \
                                   O1.x, O1.y, O1.z, O1.w,                      \
                                   O2.x, O2.y, O2.z, O2.w};                     \
            const float mp_[4]  = {MP.x, MP.y, MP.z, MP.w};                     \
            const float mo_[4]  = {MO.x, MO.y, MO.z, MO.w};                     \
            const float sg_[4]  = {SG.x, SG.y, SG.z, SG.w};                     \
            ushort4 hv;                                                         \
            unsigned short* hp = (unsigned short*)&hv;                          \
            _Pragma("unroll")                                                   \
            for (int j = 0; j < OPT; ++j) {                                     \
                const float dx = up_[3 * j]     - uo_[3 * j];                   \
                const float dy = up_[3 * j + 1] - uo_[3 * j + 1];               \
                const float dz = up_[3 * j + 2] - uo_[3 * j + 2];               \
                const float s2 = dx * dx + dy * dy + dz * dz;                   \
                const float z  = (mp_[j] - mo_[j]) * fast_rcp(sg_[j]);          \
                const float pm = __expf(-0.5f * z * z);                         \
                const bool close = s2 < thresh;                                 \
                const float e  = close ? __expf(nlam_it * s2) : 0.f;            \
                hp[j] = __half_as_ushort(__float2half(e * pm));                 \
                cnt   += close ? 1.f : 0.f;                                     \
                pmsum += close ? pm  : 0.f;                                     \
            }                                                                   \
            ((ushort4*)(epc + base0))[(c) * 256 + t] = hv;                      \
        } while (0)

        float4 aP0, aP1, aP2, aO0, aO1, aO2, aMP, aMO, aSG;   // buffer A
        float4 bP0, bP1, bP2, bO0, bO1, bO2, bMP, bMO, bSG;   // buffer B

        LOADC(0, aP0, aP1, aP2, aO0, aO1, aO2, aMP, aMO, aSG);
        LOADC(1, bP0, bP1, bP2, bO0, bO1, bO2, bMP, bMO, bSG);
        CONSUME(0, aP0, aP1, aP2, aO0, aO1, aO2, aMP, aMO, aSG);
        LOADC(2, aP0, aP1, aP2, aO0, aO1, aO2, aMP, aMO, aSG);
        CONSUME(1, bP0, bP1, bP2, bO0, bO1, bO2, bMP, bMO, bSG);
        LOADC(3, bP0, bP1, bP2, bO0, bO1, bO2, bMP, bMO, bSG);
        CONSUME(2, aP0, aP1, aP2, aO0, aO1, aO2, aMP, aMO, aSG);
        CONSUME(3, bP0, bP1, bP2, bO0, bO1, bO2, bMP, bMO, bSG);

        #undef LOADC
        #undef CONSUME
    } else {
        // tail path: scalar with bounds checks (unused when rowLen % 4096 == 0)
        for (int c = 0; c < CPB; ++c) {
            const int off = off0 + c * CHUNK;
            if (off >= rowLen) break;
            for (int j = 0; j < OPT; ++j) {
                const int o = off + t * OPT + j;
                if (o >= rowLen) break;
                const size_t i = (size_t)(segBase + o);
                const float dx = u_pred[3 * i]     - u_obs[3 * i];
                const float dy = u_pred[3 * i + 1] - u_obs[3 * i + 1];
                const float dz = u_pred[3 * i + 2] - u_obs[3 * i + 2];
                const float s2 = dx * dx + dy * dy + dz * dz;
                const float z  = (mag_pred[i] - mag_obs[i]) * fast_rcp(sigma_mag[i]);
                const float pm = __expf(-0.5f * z * z);
                const bool close = s2 < thresh;
                const float e  = close ? __expf(nlam_it * s2) : 0.f;
                epc[i] = __float2half(e * pm);
                cnt   += close ? 1.f : 0.f;
                pmsum += close ? pm  : 0.f;
            }
        }
    }

    block_reduce2(cnt, pmsum);
    if (threadIdx.x == 0) {
        atomicAdd(&acc[2 * seg],     cnt);
        atomicAdd(&acc[2 * seg + 1], pmsum);
    }
}

// ---------------------------------------------------------------------------
// Pass 2: stream the 2 B/obs cache (L2/L3-resident); log_like and hits.
// ---------------------------------------------------------------------------
__global__ __launch_bounds__(BLOCK)
void pass2_kernel(const float* __restrict__ num_hits,
                  const float* __restrict__ Rparam,
                  const float* __restrict__ thresh_raw,
                  const float* __restrict__ log_range,
                  const float* __restrict__ acc,
                  const __half* __restrict__ epc,
                  float* __restrict__ out, int B,
                  int rowLen, int blocksPerSeg, float ts2min)
{
    const int seg = blockIdx.x / blocksPerSeg;
    const int blk = blockIdx.x - seg * blocksPerSeg;
    const long long segBase = (long long)seg * rowLen;

    const float thresh     = ts2min * __expf(thresh_raw[seg] * log_range[seg]);
    const float rlc        = acc[2 * seg];
    const float h          = num_hits[seg] * fast_rcp(rlc);
    const float inv_pm_den = rlc * fast_rcp(acc[2 * seg + 1]);
    const float Rv         = Rparam[seg];
    const float lam        = 0.5f * thresh / (Rv * Rv);
    const float coef       = lam * fast_rcp(1.f - __expf(-lam));
    const float one_m_h    = 1.f - h;
    const float K1         = h * coef * inv_pm_den;   // phit = K1 * ep

    float ll = 0.f, ht = 0.f;
    const int t = threadIdx.x;

    #pragma unroll 1
    for (int c = 0; c < CPB; ++c) {
        const int off = (blk * CPB + c) * CHUNK;
        if (off >= rowLen) break;
        if (off + CHUNK <= rowLen) {
            const size_t base = (size_t)(segBase + off);
            const ushort4 hv = ((const ushort4*)(epc + base))[t];
            const unsigned short* hp = (const unsigned short*)&hv;
            #pragma unroll
            for (int j = 0; j < OPT; ++j) {
                const float e = __half2float(__ushort_as_half(hp[j]));
                if (e > 0.f) {
                    const float phit = K1 * e;
                    const float p    = phit + one_m_h;
                    ll += __logf(p);
                    ht += phit * fast_rcp(p);
                }
            }
        } else {
            for (int j = 0; j < OPT; ++j) {
                const int o = off + t * OPT + j;
                if (o >= rowLen) break;
                const float e = __half2float(epc[segBase + o]);
                if (e > 0.f) {
                    const float phit = K1 * e;
                    const float p    = phit + one_m_h;
                    ll += __logf(p);
                    ht += phit * fast_rcp(p);
                }
            }
        }
    }

    block_reduce2(ll, ht);
    if (threadIdx.x == 0) {
        atomicAdd(&out[seg],     ll);
        atomicAdd(&out[B + seg], ht);
    }
}

// ---------------------------------------------------------------------------
extern "C" void kernel_launch(void* const* d_in, const int* in_sizes, int n_in,
                              void* d_out, int out_size, void* d_ws, size_t ws_size,
                              hipStream_t stream) {
    const float* u_pred     = (const float*)d_in[0];   // [N,3]
    const float* num_hits   = (const float*)d_in[1];   // [B]
    const float* Rparam     = (const float*)d_in[2];   // [B]
    const float* mag_pred   = (const float*)d_in[3];   // [N]
    const float* sigma_mag  = (const float*)d_in[4];   // [N]
    const float* thresh_raw = (const float*)d_in[5];   // [B]
    const float* log_range  = (const float*)d_in[6];   // [B]
    const float* u_obs      = (const float*)d_in[7];   // [N,3]
    const float* mag_obs    = (const float*)d_in[8];   // [N]
    // d_in[9] segment_ids unused: segments are contiguous uniform rows

    const int B      = in_sizes[1];
    const int N      = in_sizes[3];
    const int rowLen = N / B;

    float* out = (float*)d_out;

    // ws layout: acc (2*B floats, padded to 1 KB) | fp16 ep cache [N]
    const size_t accBytes = 1024;
    float*  acc = (float*)d_ws;
    __half* epc = (__half*)((char*)d_ws + accBytes);

    const int obsPerBlock = CHUNK * CPB;
    const int blocksPerSeg = (rowLen + obsPerBlock - 1) / obsPerBlock;
    const int grid = B * blocksPerSeg;     // 2048 for rowLen=131072

    const double ang = (10.0 / 3600.0) * (M_PI / 180.0);
    const double chord = 2.0 * sin(0.5 * ang);
    const float ts2min = (float)(chord * chord);

    hipMemsetAsync(d_out, 0, (size_t)out_size * sizeof(float), stream);
    hipMemsetAsync(d_ws, 0, accBytes, stream);

    pass1_kernel<<<grid, BLOCK, 0, stream>>>(
        u_pred, u_obs, mag_pred, mag_obs, sigma_mag,
        Rparam, thresh_raw, log_range, acc, epc, rowLen, blocksPerSeg, ts2min);
    pass2_kernel<<<grid, BLOCK, 0, stream>>>(
        num_hits, Rparam, thresh_raw, log_range, acc, epc,
        out, B, rowLen, blocksPerSeg, ts2min);
}